// Round 3
// baseline (87462.439 us; speedup 1.0000x reference)
//
#include <hip/hip_runtime.h>
#include <hip/hip_fp16.h>

// RecurrentQNet: B=64, S=1024, D=64, H=512, A=16
// R4: slice-parallel persistent recurrence (R3 structure) with two fixes:
//   FIX 1 (correctness): R3's sync region was 192 u4 but flags at 32+wg*16
//     needed 2080 uints -> flags for wg>=46 overwrote the h2 exchange buffer
//     (corrupt h + spurious barrier release). Now properly sized, flat
//     all-to-all flag barrier (no relay).
//   FIX 2 (precision): back to the R2-passing recipe — f16 chains capped at
//     16 products, u exchanged in fp32, pred phase fully fp32 with fp32 cb_w2.
//     x read fp32 + packed to f16 in-register (drops the 8MB x2 buffer).
// 128 WGs x 256 thr; WG wg owns output slice j=[4wg,4wg+4) for ALL 64 batches;
// weights read once per step grid-wide (each WG's ~20KB slice is L1-resident).

#define B_ 64
#define S_ 1024
#define D_ 64
#define H_ 512
#define A_ 16

// ---- workspace layout in uint4 units ----
#define OFF_WGX   0          // [128][12][4][16] u4 : W_hh slices f16
#define OFF_WGI   98304      // [128][12][4][4]  u4 : W_ih slices f16
#define OFF_WUX   122880     // [128][4][4][16]  u4 : cb_w1 slices f16
#define OFF_SYNC  155648     // flags[128] @ stride 16 uints, dead @ uint 2048
#define OFF_H2    156192     // [2][64][64] u4 : h exchange f16, parity-buffered
#define OFF_U2    164384     // [64][512]  f32 : u exchange (8192 u4)
#define OFF_PRED2 172576     // [64][8]    u4  : pred exchange f16
#define WS_TOTAL  173088

#define NWG 128

union V16 {
    uint4   u;
    float4  f;
    __half2 h[4];
};

// ---------------- K0: one-time weight convert + zero sync/exchange ----------------
__global__ __launch_bounds__(256) void k_convert(
    const float* __restrict__ W_ih,   // [1536,128]
    const float* __restrict__ W_hh,   // [1536,512]
    const float* __restrict__ cb_w1,  // [512,512]
    uint4* __restrict__ ws)
{
    int idx = blockIdx.x * 256 + threadIdx.x;
    const float* src;
    if (idx < OFF_WGI) {                         // W_hh: [wg][r=g*4+jj][c][q]
        int wg = idx / 768, rem = idx % 768;
        int r = rem >> 6, c = (rem >> 4) & 3, q = rem & 15;
        int g = r >> 2, jj = r & 3;
        src = W_hh + (size_t)(g * 512 + wg * 4 + jj) * 512 + c * 128 + q * 8;
    } else if (idx < OFF_WUX) {                  // W_ih: [wg][r][c][q2]
        int i2 = idx - OFF_WGI;
        int wg = i2 / 192, rem = i2 % 192;
        int r = rem >> 4, c = (rem >> 2) & 3, q2 = rem & 3;
        int g = r >> 2, jj = r & 3;
        src = W_ih + (size_t)(g * 512 + wg * 4 + jj) * 128 + c * 32 + q2 * 8;
    } else if (idx < OFF_SYNC) {                 // cb_w1: [wg][jr][c][q]
        int i2 = idx - OFF_WUX;
        int wg = i2 / 256, rem = i2 % 256;
        int jr = rem >> 6, c = (rem >> 4) & 3, q = rem & 15;
        src = cb_w1 + (size_t)(wg * 4 + jr) * 512 + c * 128 + q * 8;
    } else if (idx < WS_TOTAL) {                 // zero sync + h2 + u2 + pred2
        ws[idx] = make_uint4(0u, 0u, 0u, 0u);
        return;
    } else return;
    V16 o;
#pragma unroll
    for (int i = 0; i < 4; ++i) o.h[i] = __floats2half2_rn(src[2 * i], src[2 * i + 1]);
    ws[idx] = o.u;
}

// ---------------- flat grid barrier ----------------
__device__ __forceinline__ int poll_ge(unsigned* p, unsigned bn, unsigned* dead) {
    unsigned it = 0;
    while (__hip_atomic_load(p, __ATOMIC_RELAXED, __HIP_MEMORY_SCOPE_AGENT) < bn) {
        __builtin_amdgcn_s_sleep(2);
        if ((++it & 1023u) == 0u) {
            if (__hip_atomic_load(dead, __ATOMIC_RELAXED, __HIP_MEMORY_SCOPE_AGENT) != 0u) return 1;
            if (it > (1u << 24)) {   // ~0.5s: residency failure -> bail, don't hang
                __hip_atomic_store(dead, 1u, __ATOMIC_RELAXED, __HIP_MEMORY_SCOPE_AGENT);
                return 1;
            }
        }
    }
    return 0;
}

__device__ __forceinline__ int gbar(unsigned* flags, unsigned* dead, unsigned bn,
                                    unsigned* s_flag) {
    const int tid = threadIdx.x;
    __syncthreads();                    // all this WG's stores drained (vmcnt 0)
    if (tid == 0) *s_flag = 0u;
    __syncthreads();
    if (tid == 0) {
        __builtin_amdgcn_fence(__ATOMIC_RELEASE, "agent");
        __hip_atomic_store(flags + blockIdx.x * 16, bn, __ATOMIC_RELAXED,
                           __HIP_MEMORY_SCOPE_AGENT);
    }
    if (tid < NWG) {
        if (poll_ge(flags + tid * 16, bn, dead)) *s_flag = 1u;
    }
    __syncthreads();                    // all polls done
    if (tid == 0) __builtin_amdgcn_fence(__ATOMIC_ACQUIRE, "agent");
    __syncthreads();                    // fence (L1 inv) before any data reads
    return *s_flag != 0u;
}

// ---------------- K1: slice-parallel recurrence ----------------
// thread tid: b = tid>>2 (batch), c = tid&3 (K-quarter). WG wg: j-slice 4wg..4wg+3.
__global__ __launch_bounds__(256) void k_recur(
    const uint4* __restrict__ wsb,
    unsigned* __restrict__ syncw,      // flags base; dead at +2048
    uint4* __restrict__ h2u4,          // [2][64][64] u4
    float* __restrict__ u2f,           // [64][512] f32
    uint4* __restrict__ pred2u4,       // [64][8] u4
    const float* __restrict__ x,       // [64,1024,64] fp32
    const float* __restrict__ b_ih, const float* __restrict__ b_hh,
    const float* __restrict__ cb_b1, const float* __restrict__ cb_b2,
    const float* __restrict__ cb_w2,   // [64,512] fp32
    float* __restrict__ hist,          // [64,1024,512]
    float* __restrict__ hidden,        // [64,512]
    float* __restrict__ cbp)           // [64,1024,64]
{
    __shared__ unsigned s_flag;
    const int tid = threadIdx.x;
    const int wg = blockIdx.x;
    const int b = tid >> 2;
    const int c = tid & 3;
    const int j4 = wg * 4;

    unsigned* dead = syncw + 2048;

    const uint4* wgxP = wsb + OFF_WGX + wg * 768 + c * 16;   // [r*64 + q]
    const uint4* wgiP = wsb + OFF_WGI + wg * 192 + c * 4;    // [r*16 + q2]
    const uint4* wuxP = wsb + OFF_WUX + wg * 256 + c * 16;   // [r*64 + q]

    float bias_r[4], bias_z[4], bias_ni[4], bias_nh[4], bias_u[4];
#pragma unroll
    for (int jj = 0; jj < 4; ++jj) {
        int j = j4 + jj;
        bias_r[jj]  = b_ih[j] + b_hh[j];
        bias_z[jj]  = b_ih[512 + j] + b_hh[512 + j];
        bias_ni[jj] = b_ih[1024 + j];
        bias_nh[jj] = b_hh[1024 + j];
        bias_u[jj]  = cb_b1[j];
    }
    const int dl = tid >> 3, oct = tid & 7;
    const int pb = wg >> 1, d = (wg & 1) * 32 + dl;
    const float bias_p = cb_b2[d];

    float hprev[4] = {0.f, 0.f, 0.f, 0.f};

    const uint4* hrow0 = h2u4 + b * 64 + c * 16;          // parity 0
    const uint4* hrow1 = h2u4 + 4096 + b * 64 + c * 16;   // parity 1
    uint2* h2w0 = (uint2*)h2u4 + b * 128 + wg;
    uint2* h2w1 = ((uint2*)(h2u4 + 4096)) + b * 128 + wg;
    __half* pred2h = (__half*)pred2u4;

    unsigned bn = 0;

    for (int t = 0; t < S_; ++t) {
        const int par = t & 1;

        // ======== phase 1: gates (f16 chains of 16 products, f32 flush) ========
        float accf[16];
#pragma unroll
        for (int i = 0; i < 16; ++i) accf[i] = 0.f;
        {
            const uint4* aP = par ? hrow0 : hrow1;   // h_{t-1}
#pragma unroll
            for (int grp = 0; grp < 8; ++grp) {      // hh part: 2 uint4 per flush
                __half2 ha[12];
#pragma unroll
                for (int r = 0; r < 12; ++r) ha[r] = __float2half2_rn(0.f);
#pragma unroll
                for (int qq = 0; qq < 2; ++qq) {
                    const int q = grp * 2 + qq;
                    V16 a; a.u = aP[q];
#pragma unroll
                    for (int r = 0; r < 12; ++r) {
                        V16 w; w.u = wgxP[r * 64 + q];
                        ha[r] = __hfma2(w.h[0], a.h[0], ha[r]);
                        ha[r] = __hfma2(w.h[1], a.h[1], ha[r]);
                        ha[r] = __hfma2(w.h[2], a.h[2], ha[r]);
                        ha[r] = __hfma2(w.h[3], a.h[3], ha[r]);
                    }
                }
#pragma unroll
                for (int r = 0; r < 12; ++r) {
                    float2 f = __half22float2(ha[r]);
                    accf[r] += f.x + f.y;
                }
            }
            // gi part: K=128 over [x_t | pred_{t-1}]; n-gate gi -> accf[12..15]
            V16 a4[4];
            if (c < 2) {
                const float4* xp = (const float4*)(x + ((size_t)b * S_ + t) * D_ + c * 32);
#pragma unroll
                for (int q2 = 0; q2 < 4; ++q2) {
                    float4 f0 = xp[q2 * 2], f1 = xp[q2 * 2 + 1];
                    a4[q2].h[0] = __floats2half2_rn(f0.x, f0.y);
                    a4[q2].h[1] = __floats2half2_rn(f0.z, f0.w);
                    a4[q2].h[2] = __floats2half2_rn(f1.x, f1.y);
                    a4[q2].h[3] = __floats2half2_rn(f1.z, f1.w);
                }
            } else {
#pragma unroll
                for (int q2 = 0; q2 < 4; ++q2) a4[q2].u = pred2u4[b * 8 + (c - 2) * 4 + q2];
            }
#pragma unroll
            for (int g2 = 0; g2 < 2; ++g2) {
                __half2 hb[12];
#pragma unroll
                for (int r = 0; r < 12; ++r) hb[r] = __float2half2_rn(0.f);
#pragma unroll
                for (int qq = 0; qq < 2; ++qq) {
                    const int q2 = g2 * 2 + qq;
                    V16 a = a4[q2];
#pragma unroll
                    for (int r = 0; r < 12; ++r) {
                        V16 w; w.u = wgiP[r * 16 + q2];
                        hb[r] = __hfma2(w.h[0], a.h[0], hb[r]);
                        hb[r] = __hfma2(w.h[1], a.h[1], hb[r]);
                        hb[r] = __hfma2(w.h[2], a.h[2], hb[r]);
                        hb[r] = __hfma2(w.h[3], a.h[3], hb[r]);
                    }
                }
#pragma unroll
                for (int r = 0; r < 12; ++r) {
                    float2 f = __half22float2(hb[r]);
                    float v = f.x + f.y;
                    if (r < 8) accf[r] += v;
                    else       accf[12 + (r - 8)] += v;
                }
            }
        }
#pragma unroll
        for (int i = 0; i < 16; ++i) {
            accf[i] += __shfl_xor(accf[i], 1);
            accf[i] += __shfl_xor(accf[i], 2);
        }
        if (c == 0) {
            float h[4];
#pragma unroll
            for (int jj = 0; jj < 4; ++jj) {
                float rr = 1.f / (1.f + __expf(-(accf[jj] + bias_r[jj])));
                float zz = 1.f / (1.f + __expf(-(accf[4 + jj] + bias_z[jj])));
                float nn = tanhf(accf[12 + jj] + bias_ni[jj] + rr * (accf[8 + jj] + bias_nh[jj]));
                h[jj] = (1.f - zz) * nn + zz * hprev[jj];
                hprev[jj] = h[jj];
            }
            *(float4*)(hist + ((size_t)b * S_ + t) * H_ + j4) = make_float4(h[0], h[1], h[2], h[3]);
            if (t == S_ - 1)
                *(float4*)(hidden + (size_t)b * H_ + j4) = make_float4(h[0], h[1], h[2], h[3]);
            __half2 p0 = __floats2half2_rn(h[0], h[1]);
            __half2 p1 = __floats2half2_rn(h[2], h[3]);
            uint2 pk; pk.x = *(unsigned*)&p0; pk.y = *(unsigned*)&p1;
            *(par ? h2w1 : h2w0) = pk;
        }
        ++bn; if (gbar(syncw, dead, bn, &s_flag)) return;

        // ======== phase 2: u = relu(cb_w1 @ h_t + b1), u kept fp32 ========
        {
            const uint4* aC = par ? hrow1 : hrow0;   // h_t
            float uacc[4] = {0.f, 0.f, 0.f, 0.f};
#pragma unroll
            for (int grp = 0; grp < 8; ++grp) {
                __half2 ha[4];
#pragma unroll
                for (int r = 0; r < 4; ++r) ha[r] = __float2half2_rn(0.f);
#pragma unroll
                for (int qq = 0; qq < 2; ++qq) {
                    const int q = grp * 2 + qq;
                    V16 a; a.u = aC[q];
#pragma unroll
                    for (int r = 0; r < 4; ++r) {
                        V16 w; w.u = wuxP[r * 64 + q];
                        ha[r] = __hfma2(w.h[0], a.h[0], ha[r]);
                        ha[r] = __hfma2(w.h[1], a.h[1], ha[r]);
                        ha[r] = __hfma2(w.h[2], a.h[2], ha[r]);
                        ha[r] = __hfma2(w.h[3], a.h[3], ha[r]);
                    }
                }
#pragma unroll
                for (int r = 0; r < 4; ++r) { float2 f = __half22float2(ha[r]); uacc[r] += f.x + f.y; }
            }
#pragma unroll
            for (int r = 0; r < 4; ++r) {
                uacc[r] += __shfl_xor(uacc[r], 1);
                uacc[r] += __shfl_xor(uacc[r], 2);
            }
            if (c == 0) {
                float u0 = fmaxf(uacc[0] + bias_u[0], 0.f);
                float u1 = fmaxf(uacc[1] + bias_u[1], 0.f);
                float u2v = fmaxf(uacc[2] + bias_u[2], 0.f);
                float u3 = fmaxf(uacc[3] + bias_u[3], 0.f);
                *(float4*)(u2f + (size_t)b * 512 + j4) = make_float4(u0, u1, u2v, u3);
            }
        }
        ++bn; if (gbar(syncw, dead, bn, &s_flag)) return;

        // ======== phase 3: pred = cb_w2 @ u + b2, fully fp32 ========
        {
            float pacc = 0.f;
            const float4* uv = (const float4*)(u2f + (size_t)pb * 512 + oct * 64);
            const float4* wv = (const float4*)(cb_w2 + (size_t)d * 512 + oct * 64);
#pragma unroll
            for (int i = 0; i < 16; ++i) {
                float4 a = uv[i], w = wv[i];
                pacc += a.x * w.x + a.y * w.y + a.z * w.z + a.w * w.w;
            }
            pacc += __shfl_xor(pacc, 1);
            pacc += __shfl_xor(pacc, 2);
            pacc += __shfl_xor(pacc, 4);
            if (oct == 0) {
                float pv = pacc + bias_p;
                cbp[((size_t)pb * S_ + t) * 64 + d] = pv;
                pred2h[pb * 64 + d] = __float2half(pv);
            }
        }
        ++bn; if (gbar(syncw, dead, bn, &s_flag)) return;
    }
}

// ---------------- E1: ca1 = relu(h @ fc_w.T + fc_b), IN PLACE (unchanged) ----------------
__global__ __launch_bounds__(256) void k_fc_inplace(
    float* __restrict__ hist,        // in: h rows, out: ca1 rows  [65536,512]
    const float* __restrict__ fc_w,  // [512,512]
    const float* __restrict__ fc_b)  // [512]
{
    __shared__ __align__(16) float s_a[16 * 516];
    const int tid = threadIdx.x;
    const int r = tid & 15;
    const int jset = tid >> 4;
    const int row0 = blockIdx.x * 16;

    for (int i = tid; i < 2048; i += 256) {
        int rr = i >> 7, f = i & 127;
        float4 v = *(const float4*)(hist + (size_t)(row0 + rr) * H_ + f * 4);
        *(float4*)(s_a + rr * 516 + f * 4) = v;
    }
    __syncthreads();

    float acc[32];
#pragma unroll
    for (int jj = 0; jj < 32; ++jj) acc[jj] = 0.f;

    const float4* arow = (const float4*)(s_a + r * 516);
    for (int k4 = 0; k4 < 128; ++k4) {
        float4 a = arow[k4];
#pragma unroll
        for (int jj = 0; jj < 32; ++jj) {
            int j = jset + (jj << 4);
            float4 w = *(const float4*)(fc_w + (size_t)j * 512 + k4 * 4);
            acc[jj] += a.x * w.x + a.y * w.y + a.z * w.z + a.w * w.w;
        }
    }

    float* crow = hist + (size_t)(row0 + r) * H_;
#pragma unroll
    for (int jj = 0; jj < 32; ++jj) {
        int j = jset + (jj << 4);
        float v = acc[jj] + fc_b[j];
        crow[j] = fmaxf(v, 0.f);
    }
}

// ---------------- E3: q = ca1 @ out_w.T + out_b (unchanged) ----------------
__global__ __launch_bounds__(256) void k_q(
    const float* __restrict__ ca1,   // [65536,512]
    const float* __restrict__ out_w, // [16,512]
    const float* __restrict__ out_b, // [16]
    float* __restrict__ q)           // [65536,16]
{
    __shared__ __align__(16) float s_a[16 * 516];
    __shared__ __align__(16) float s_w[16 * 516];
    const int tid = threadIdx.x;
    const int r = tid >> 4;
    const int a_ = tid & 15;
    const int row0 = blockIdx.x * 16;

    for (int i = tid; i < 2048; i += 256) {
        int rr = i >> 7, f = i & 127;
        float4 v = *(const float4*)(ca1 + (size_t)(row0 + rr) * H_ + f * 4);
        *(float4*)(s_a + rr * 516 + f * 4) = v;
    }
    for (int i = tid; i < 2048; i += 256) {
        int rr = i >> 7, f = i & 127;
        float4 v = *(const float4*)(out_w + (size_t)rr * 512 + f * 4);
        *(float4*)(s_w + rr * 516 + f * 4) = v;
    }
    __syncthreads();

    const float4* arow = (const float4*)(s_a + r * 516);
    const float4* wrow = (const float4*)(s_w + a_ * 516);
    float acc = 0.f;
#pragma unroll 8
    for (int k4 = 0; k4 < 128; ++k4) {
        float4 a = arow[k4];
        float4 w = wrow[k4];
        acc += a.x * w.x + a.y * w.y + a.z * w.z + a.w * w.w;
    }
    q[(size_t)(row0 + r) * A_ + a_] = acc + out_b[a_];
}

// ---------------- host ----------------
extern "C" void kernel_launch(void* const* d_in, const int* in_sizes, int n_in,
                              void* d_out, int out_size, void* d_ws, size_t ws_size,
                              hipStream_t stream) {
    const float* x     = (const float*)d_in[0];
    const float* W_ih  = (const float*)d_in[1];
    const float* W_hh  = (const float*)d_in[2];
    const float* b_ih  = (const float*)d_in[3];
    const float* b_hh  = (const float*)d_in[4];
    const float* fc_w  = (const float*)d_in[5];
    const float* fc_b  = (const float*)d_in[6];
    const float* out_w = (const float*)d_in[7];
    const float* out_b = (const float*)d_in[8];
    const float* cb_w1 = (const float*)d_in[9];
    const float* cb_b1 = (const float*)d_in[10];
    const float* cb_w2 = (const float*)d_in[11];
    const float* cb_b2 = (const float*)d_in[12];

    float* q_out  = (float*)d_out;                     // [64,1024,16]
    float* cbp    = q_out + (size_t)B_ * S_ * A_;      // [64,1024,64]
    float* hidden = cbp + (size_t)B_ * S_ * D_;        // [1,64,512]
    float* ca1    = hidden + (size_t)B_ * H_;          // [64,1024,512] (h-history then ca1)

    uint4* wsu = (uint4*)d_ws;                         // 173088 u4 = 2.77 MB

    k_convert<<<(WS_TOTAL + 255) / 256, 256, 0, stream>>>(W_ih, W_hh, cb_w1, wsu);
    k_recur<<<NWG, 256, 0, stream>>>(wsu,
        (unsigned*)(wsu + OFF_SYNC), wsu + OFF_H2, (float*)(wsu + OFF_U2),
        wsu + OFF_PRED2, x, b_ih, b_hh, cb_b1, cb_b2, cb_w2, ca1, hidden, cbp);
    k_fc_inplace<<<4096, 256, 0, stream>>>(ca1, fc_w, fc_b);
    k_q<<<4096, 256, 0, stream>>>(ca1, out_w, out_b, q_out);
}